// Round 7
// baseline (385.140 us; speedup 1.0000x reference)
//
#include <hip/hip_runtime.h>
#include <hip/hip_bf16.h>

// Problem constants: B=2, S=2048, D=1024, H=16, A=64
#define B_ 2
#define S_ 2048
#define D_ 1024
#define H_ 16
#define A_ 64

typedef __attribute__((ext_vector_type(8))) short bf16x8;
typedef __attribute__((ext_vector_type(4))) float f32x4;

#define QSCALE 0.1803368801111204f   // 1/sqrt(64) * log2(e): softmax done in exp2 domain

__device__ inline short f2bf(float f) {
    union { float f; unsigned u; } x; x.f = f;
    unsigned r = x.u + 0x7fff + ((x.u >> 16) & 1);   // RNE
    return (short)(r >> 16);
}

// 16-lane butterfly reductions on the VALU via DPP (proven in R5) — LDS pipe stays free.
__device__ inline float dpp_max16(float x) {
    int v;
    v = __builtin_amdgcn_update_dpp(0, __builtin_bit_cast(int, x), 0xB1, 0xF, 0xF, false);
    x = fmaxf(x, __builtin_bit_cast(float, v));
    v = __builtin_amdgcn_update_dpp(0, __builtin_bit_cast(int, x), 0x4E, 0xF, 0xF, false);
    x = fmaxf(x, __builtin_bit_cast(float, v));
    v = __builtin_amdgcn_update_dpp(0, __builtin_bit_cast(int, x), 0x141, 0xF, 0xF, false);
    x = fmaxf(x, __builtin_bit_cast(float, v));
    v = __builtin_amdgcn_update_dpp(0, __builtin_bit_cast(int, x), 0x140, 0xF, 0xF, false);
    x = fmaxf(x, __builtin_bit_cast(float, v));
    return x;
}
__device__ inline float dpp_sum16(float x) {
    int v;
    v = __builtin_amdgcn_update_dpp(0, __builtin_bit_cast(int, x), 0xB1, 0xF, 0xF, false);
    x += __builtin_bit_cast(float, v);
    v = __builtin_amdgcn_update_dpp(0, __builtin_bit_cast(int, x), 0x4E, 0xF, 0xF, false);
    x += __builtin_bit_cast(float, v);
    v = __builtin_amdgcn_update_dpp(0, __builtin_bit_cast(int, x), 0x141, 0xF, 0xF, false);
    x += __builtin_bit_cast(float, v);
    v = __builtin_amdgcn_update_dpp(0, __builtin_bit_cast(int, x), 0x140, 0xF, 0xF, false);
    x += __builtin_bit_cast(float, v);
    return x;
}

// ---------------- kernel 1: fp32 -> bf16 cast of residual ----------------
__global__ __launch_bounds__(256) void cast_kernel(const float* __restrict__ x,
                                                   short* __restrict__ y, int n) {
    int i = (blockIdx.x * 256 + threadIdx.x) * 8;
    if (i < n) {
        float4 a = *(const float4*)(x + i);
        float4 b = *(const float4*)(x + i + 4);
        bf16x8 o;
        o[0]=f2bf(a.x); o[1]=f2bf(a.y); o[2]=f2bf(a.z); o[3]=f2bf(a.w);
        o[4]=f2bf(b.x); o[5]=f2bf(b.y); o[6]=f2bf(b.z); o[7]=f2bf(b.w);
        *(bf16x8*)(y + i) = o;
    }
}

// ---------------- kernel 1b: transpose+cast weights to bf16 [n][k] ----------------
__global__ __launch_bounds__(256) void wtrans_kernel(
    const float* __restrict__ Wq, const float* __restrict__ Wk,
    const float* __restrict__ Wv, const float* __restrict__ Wo,
    short* __restrict__ Wt, short* __restrict__ Wot) {
    const int kt = blockIdx.x, yy = blockIdx.y, z = blockIdx.z;
    __shared__ short T[64 * 72];
    const int tid = threadIdx.x;
    const int r = tid >> 2, c0 = (tid & 3) * 16;
    const float* src;
    if (z < 3) {
        const float* W = z == 0 ? Wq : (z == 1 ? Wk : Wv);
        src = &W[yy * (D_ * A_) + (kt * 64 + r) * A_ + c0];
    } else {
        src = &Wo[(kt * 64 + r) * D_ + yy * 64 + c0];
    }
    #pragma unroll
    for (int q = 0; q < 4; q++) {
        float4 f = *(const float4*)(src + q * 4);
        T[r * 72 + c0 + q * 4 + 0] = f2bf(f.x);
        T[r * 72 + c0 + q * 4 + 1] = f2bf(f.y);
        T[r * 72 + c0 + q * 4 + 2] = f2bf(f.z);
        T[r * 72 + c0 + q * 4 + 3] = f2bf(f.w);
    }
    __syncthreads();
    const int a = tid >> 2, kc = (tid & 3) * 16;
    bf16x8 o0, o1;
    #pragma unroll
    for (int j = 0; j < 8; j++) {
        o0[j] = T[(kc + j) * 72 + a];
        o1[j] = T[(kc + 8 + j) * 72 + a];
    }
    const int n_base = (z < 3) ? z * 1024 + yy * 64 : yy * 64;
    short* dst = (z < 3) ? &Wt[(n_base + a) * D_ + kt * 64 + kc]
                         : &Wot[(n_base + a) * D_ + kt * 64 + kc];
    *(bf16x8*)dst = o0;
    *(bf16x8*)(dst + 8) = o1;
}

// ---------------- kernel 2: QKV as one GEMM [4096 x 3072 x 1024] ----------------
__global__ __launch_bounds__(256) void qkv_gemm(
    const short* __restrict__ X, const short* __restrict__ Wt,
    const float* __restrict__ bq, const float* __restrict__ bk, const float* __restrict__ bv,
    short* __restrict__ Qb, short* __restrict__ Kb, short* __restrict__ Vt) {
    const int mt = blockIdx.x, nt = blockIdx.y;
    const int m0 = mt * 128, n0 = nt * 128;
    const int sel = n0 >> 10;
    __shared__ short Xl[2][128 * 40], Wl[2][128 * 40];
    const int tid = threadIdx.x, wv = tid >> 6, lane = tid & 63, quad = lane >> 4, l16 = lane & 15;
    const int grow = tid >> 1, gk = (tid & 1) * 16;
    f32x4 acc[4][4] = {};
    bf16x8 xr0, xr1, wr0, wr1;
    {
        const short* xs = &X[(m0 + grow) * D_ + gk];
        xr0 = *(const bf16x8*)xs; xr1 = *(const bf16x8*)(xs + 8);
        const short* wsp = &Wt[(n0 + grow) * D_ + gk];
        wr0 = *(const bf16x8*)wsp; wr1 = *(const bf16x8*)(wsp + 8);
    }
    const int rm = (wv & 1) * 64, cn = (wv >> 1) * 64;
    for (int i = 0; i < 32; i++) {
        const int bu = i & 1;
        *(bf16x8*)&Xl[bu][grow * 40 + gk]     = xr0;
        *(bf16x8*)&Xl[bu][grow * 40 + gk + 8] = xr1;
        *(bf16x8*)&Wl[bu][grow * 40 + gk]     = wr0;
        *(bf16x8*)&Wl[bu][grow * 40 + gk + 8] = wr1;
        __syncthreads();
        if (i < 31) {
            const int k0 = (i + 1) * 32;
            const short* xs = &X[(m0 + grow) * D_ + k0 + gk];
            xr0 = *(const bf16x8*)xs; xr1 = *(const bf16x8*)(xs + 8);
            const short* wsp = &Wt[(n0 + grow) * D_ + k0 + gk];
            wr0 = *(const bf16x8*)wsp; wr1 = *(const bf16x8*)(wsp + 8);
        }
        bf16x8 af[4];
        #pragma unroll
        for (int rt = 0; rt < 4; rt++)
            af[rt] = *(bf16x8*)&Xl[bu][(rm + rt * 16 + l16) * 40 + quad * 8];
        #pragma unroll
        for (int ct = 0; ct < 4; ct++) {
            bf16x8 bf = *(bf16x8*)&Wl[bu][(cn + ct * 16 + l16) * 40 + quad * 8];
            #pragma unroll
            for (int rt = 0; rt < 4; rt++)
                acc[rt][ct] = __builtin_amdgcn_mfma_f32_16x16x32_bf16(af[rt], bf, acc[rt][ct], 0, 0, 0);
        }
    }
    const int b = m0 >> 11;
    const float* bias = sel == 0 ? bq : (sel == 1 ? bk : bv);
    if (sel < 2) {
        short* dst = sel == 0 ? Qb : Kb;
        const float scale = sel == 0 ? QSCALE : 1.0f;
        #pragma unroll
        for (int ct = 0; ct < 4; ct++) {
            const int n = n0 + cn + ct * 16 + l16;
            const int h = (n >> 6) & 15, a = n & 63;
            const float bi = bias[n & 1023];
            #pragma unroll
            for (int rt = 0; rt < 4; rt++)
                #pragma unroll
                for (int r = 0; r < 4; r++) {
                    const int row = m0 + rm + rt * 16 + quad * 4 + r;
                    const int s = row & (S_ - 1);
                    dst[(((b * H_) + h) * S_ + s) * A_ + a] = f2bf((acc[rt][ct][r] + bi) * scale);
                }
        }
    } else {
        #pragma unroll
        for (int ct = 0; ct < 4; ct++) {
            const int n = n0 + cn + ct * 16 + l16;
            const int h = (n >> 6) & 15, a = n & 63;
            const float bi = bias[n & 1023];
            #pragma unroll
            for (int rt = 0; rt < 4; rt++) {
                short4 pk;
                pk.x = f2bf(acc[rt][ct][0] + bi);
                pk.y = f2bf(acc[rt][ct][1] + bi);
                pk.z = f2bf(acc[rt][ct][2] + bi);
                pk.w = f2bf(acc[rt][ct][3] + bi);
                const int row = m0 + rm + rt * 16 + quad * 4;
                const int s = row & (S_ - 1);
                *(short4*)&Vt[(((b * H_) + h) * A_ + a) * S_ + s] = pk;
            }
        }
    }
}

// ---------------- kernel 3: flash attention — unpaired, global K/V frags, no barriers ----------------
// Proven components only: R4's global->VGPR K/V fragment pattern (correct when not
// register-capped) + R5's frag-linear P pack (verified-by-pass). One q-tile per block,
// grid (32,16,2)=1024 blocks, qt = 31-bx longest-first; waves fully independent, LDS=8KB.
__global__ __launch_bounds__(256) void flash_kernel(
    const short* __restrict__ Qb, const short* __restrict__ Kb,
    const short* __restrict__ Vt, short* __restrict__ Z) {
    const int qt = 31 - blockIdx.x, h = blockIdx.y, b = blockIdx.z;
    const int bh = b * H_ + h;
    __shared__ short Pl[4][1024];
    const int tid = threadIdx.x, wv = tid >> 6, lane = tid & 63, quad = lane >> 4, l16 = lane & 15;
    short* Pw = &Pl[wv][0];
    // frag-linear P pack base (R5, verified): value (ct,r) of lane (quad,l16) lands so that
    // A-frag read slot kk*64+lane yields P[qrow=l16][kcol=kk*32+quad*8+j]
    const int pbase = (l16 >> 3) * 128 + quad * 32 + (l16 & 7);

    // Q A-fragments in registers (Q pre-scaled by QSCALE in qkv_gemm)
    const short* qptr = &Qb[(bh * S_ + qt * 64 + wv * 16 + l16) * A_ + quad * 8];
    bf16x8 qf[2] = { *(const bf16x8*)qptr, *(const bf16x8*)(qptr + 32) };

    f32x4 O[4] = {};
    float m_i[4], l_i[4];
    #pragma unroll
    for (int r = 0; r < 4; r++) { m_i[r] = -1e30f; l_i[r] = 0.f; }

    for (int kt = 0; kt <= qt; kt++) {
        // K fragments straight from global (L1/L2-hot; 16B/lane line-aligned)
        const short* kbase = &Kb[(bh * S_ + kt * 64 + l16) * A_ + quad * 8];
        f32x4 sacc[4];
        #pragma unroll
        for (int ct = 0; ct < 4; ct++) {
            const short* kp = kbase + ct * 16 * A_;
            bf16x8 k0 = *(const bf16x8*)kp;
            bf16x8 k1 = *(const bf16x8*)(kp + 32);
            f32x4 acc = {};
            acc = __builtin_amdgcn_mfma_f32_16x16x32_bf16(qf[0], k0, acc, 0, 0, 0);
            acc = __builtin_amdgcn_mfma_f32_16x16x32_bf16(qf[1], k1, acc, 0, 0, 0);
            sacc[ct] = acc;
        }
        if (kt == qt) {   // diagonal: causal mask (log2-domain scores)
            #pragma unroll
            for (int ct = 0; ct < 4; ct++) {
                const int cl = ct * 16 + l16;
                #pragma unroll
                for (int r = 0; r < 4; r++)
                    if (cl > wv * 16 + quad * 4 + r) sacc[ct][r] = -1e30f;
            }
        }
        // online softmax: rows at (quad, r), kcol dim spans (ct, l16) -> DPP reduce across l16
        #pragma unroll
        for (int r = 0; r < 4; r++) {
            float v = fmaxf(fmaxf(sacc[0][r], sacc[1][r]), fmaxf(sacc[2][r], sacc[3][r]));
            v = dpp_max16(v);
            const float mn = fmaxf(m_i[r], v);
            const float alpha = exp2f(m_i[r] - mn);
            float rs = 0.f;
            #pragma unroll
            for (int ct = 0; ct < 4; ct++) {
                const float pe = exp2f(sacc[ct][r] - mn);
                sacc[ct][r] = pe; rs += pe;
            }
            l_i[r] = l_i[r] * alpha + rs;   // per-lane partial (this lane's 4 kcols); epilogue reduces
            m_i[r] = mn;
            #pragma unroll
            for (int ct = 0; ct < 4; ct++) O[ct][r] *= alpha;
        }
        // V B-fragments from global (issued before P pack so latency overlaps it)
        bf16x8 vf[4][2];
        #pragma unroll
        for (int ct = 0; ct < 4; ct++) {
            const short* vp = &Vt[(bh * A_ + ct * 16 + l16) * S_ + kt * 64 + quad * 8];
            vf[ct][0] = *(const bf16x8*)vp;
            vf[ct][1] = *(const bf16x8*)(vp + 32);
        }
        // P: C-layout -> A-frag-linear wave-private LDS (R5-verified pack)
        #pragma unroll
        for (int ct = 0; ct < 4; ct++) {
            const int cb = pbase + (ct >> 1) * 512 + (ct & 1) * 256;
            #pragma unroll
            for (int r = 0; r < 4; r++)
                Pw[cb + r * 8] = f2bf(sacc[ct][r]);
        }
        __builtin_amdgcn_s_waitcnt(0xC07F);   // lgkmcnt(0): wave-private LDS dep
        bf16x8 pa0 = *(bf16x8*)&Pw[lane * 8];
        bf16x8 pa1 = *(bf16x8*)&Pw[(64 + lane) * 8];
        #pragma unroll
        for (int ct = 0; ct < 4; ct++) {
            O[ct] = __builtin_amdgcn_mfma_f32_16x16x32_bf16(pa0, vf[ct][0], O[ct], 0, 0, 0);
            O[ct] = __builtin_amdgcn_mfma_f32_16x16x32_bf16(pa1, vf[ct][1], O[ct], 0, 0, 0);
        }
    }
    // epilogue: reduce l partials across l16, write Z[b, s, h*64+a]
    float lsum[4];
    #pragma unroll
    for (int r = 0; r < 4; r++) lsum[r] = dpp_sum16(l_i[r]);
    #pragma unroll
    for (int ct = 0; ct < 4; ct++) {
        const int a = ct * 16 + l16;
        #pragma unroll
        for (int r = 0; r < 4; r++) {
            const int s = qt * 64 + wv * 16 + quad * 4 + r;
            Z[(b * S_ + s) * (H_ * A_) + h * A_ + a] = f2bf(O[ct][r] / lsum[r]);
        }
    }
}

// ---------------- kernel 4: output projection GEMM [4096 x 1024 x 1024] ----------------
__global__ __launch_bounds__(256) void proj_gemm(
    const short* __restrict__ Zb, const short* __restrict__ Wot,
    const float* __restrict__ bo, float* __restrict__ out) {
    const int mt = blockIdx.x, nt = blockIdx.y;
    const int m0 = mt * 128, n0 = nt * 128;
    __shared__ short Xl[2][128 * 40], Wl[2][128 * 40];
    const int tid = threadIdx.x, wv = tid >> 6, lane = tid & 63, quad = lane >> 4, l16 = lane & 15;
    const int grow = tid >> 1, gk = (tid & 1) * 16;
    f32x4 acc[4][4] = {};
    bf16x8 xr0, xr1, wr0, wr1;
    {
        const short* xs = &Zb[(m0 + grow) * D_ + gk];
        xr0 = *(const bf16x8*)xs; xr1 = *(const bf16x8*)(xs + 8);
        const short* wsp = &Wot[(n0 + grow) * D_ + gk];
        wr0 = *(const bf16x8*)wsp; wr1 = *(const bf16x8*)(wsp + 8);
    }
    const int rm = (wv & 1) * 64, cn = (wv >> 1) * 64;
    for (int i = 0; i < 32; i++) {
        const int bu = i & 1;
        *(bf16x8*)&Xl[bu][grow * 40 + gk]     = xr0;
        *(bf16x8*)&Xl[bu][grow * 40 + gk + 8] = xr1;
        *(bf16x8*)&Wl[bu][grow * 40 + gk]     = wr0;
        *(bf16x8*)&Wl[bu][grow * 40 + gk + 8] = wr1;
        __syncthreads();
        if (i < 31) {
            const int k0 = (i + 1) * 32;
            const short* xs = &Zb[(m0 + grow) * D_ + k0 + gk];
            xr0 = *(const bf16x8*)xs; xr1 = *(const bf16x8*)(xs + 8);
            const short* wsp = &Wot[(n0 + grow) * D_ + k0 + gk];
            wr0 = *(const bf16x8*)wsp; wr1 = *(const bf16x8*)(wsp + 8);
        }
        bf16x8 af[4];
        #pragma unroll
        for (int rt = 0; rt < 4; rt++)
            af[rt] = *(bf16x8*)&Xl[bu][(rm + rt * 16 + l16) * 40 + quad * 8];
        #pragma unroll
        for (int ct = 0; ct < 4; ct++) {
            bf16x8 bf = *(bf16x8*)&Wl[bu][(cn + ct * 16 + l16) * 40 + quad * 8];
            #pragma unroll
            for (int rt = 0; rt < 4; rt++)
                acc[rt][ct] = __builtin_amdgcn_mfma_f32_16x16x32_bf16(af[rt], bf, acc[rt][ct], 0, 0, 0);
        }
    }
    #pragma unroll
    for (int ct = 0; ct < 4; ct++) {
        const int n = n0 + cn + ct * 16 + l16;
        const float bi = bo[n];
        #pragma unroll
        for (int rt = 0; rt < 4; rt++)
            #pragma unroll
            for (int r = 0; r < 4; r++) {
                const int row = m0 + rm + rt * 16 + quad * 4 + r;
                out[row * D_ + n] = acc[rt][ct][r] + bi;
            }
    }
}

extern "C" void kernel_launch(void* const* d_in, const int* in_sizes, int n_in,
                              void* d_out, int out_size, void* d_ws, size_t ws_size,
                              hipStream_t stream) {
    const float* residual = (const float*)d_in[0];
    const float* Wq = (const float*)d_in[1];
    const float* Wk = (const float*)d_in[2];
    const float* Wv = (const float*)d_in[3];
    const float* Wo = (const float*)d_in[4];
    const float* bq = (const float*)d_in[5];
    const float* bk = (const float*)d_in[6];
    const float* bv = (const float*)d_in[7];
    const float* bo = (const float*)d_in[8];
    float* out = (float*)d_out;

    char* ws = (char*)d_ws;
    const size_t NE = (size_t)B_ * S_ * D_;           // 4,194,304
    short* Xbf = (short*)(ws);                        //  8 MB  [B*S, D] bf16
    short* Wt  = (short*)(ws +  8ull * 1024 * 1024);  //  6 MB  [3072, 1024] bf16 (qkv, transposed)
    short* Wot = (short*)(ws + 14ull * 1024 * 1024);  //  2 MB  [1024, 1024] bf16 (Wo, transposed)
    short* Qb  = (short*)(ws + 16ull * 1024 * 1024);  //  8 MB  [B,H,S,A]
    short* Kb  = (short*)(ws + 24ull * 1024 * 1024);  //  8 MB  [B,H,S,A]
    short* Vt  = (short*)(ws + 32ull * 1024 * 1024);  //  8 MB  [B,H,A,S]
    short* Zb  = (short*)(ws + 40ull * 1024 * 1024);  //  8 MB  [B,S,H*A]

    hipLaunchKernelGGL(cast_kernel, dim3((int)(NE / (256 * 8))), dim3(256), 0, stream,
                       residual, Xbf, (int)NE);
    hipLaunchKernelGGL(wtrans_kernel, dim3(16, 16, 4), dim3(256), 0, stream,
                       Wq, Wk, Wv, Wo, Wt, Wot);
    hipLaunchKernelGGL(qkv_gemm, dim3(32, 24), dim3(256), 0, stream,
                       Xbf, Wt, bq, bk, bv, Qb, Kb, Vt);
    hipLaunchKernelGGL(flash_kernel, dim3(32, H_, B_), dim3(256), 0, stream,
                       Qb, Kb, Vt, Zb);
    hipLaunchKernelGGL(proj_gemm, dim3(32, 8), dim3(256), 0, stream,
                       Zb, Wot, bo, out);
}

// Round 8
// 212.968 us; speedup vs baseline: 1.8084x; 1.8084x over previous
//
#include <hip/hip_runtime.h>
#include <hip/hip_bf16.h>

// Problem constants: B=2, S=2048, D=1024, H=16, A=64
#define B_ 2
#define S_ 2048
#define D_ 1024
#define H_ 16
#define A_ 64

typedef __attribute__((ext_vector_type(8))) short bf16x8;
typedef __attribute__((ext_vector_type(4))) float f32x4;

#define QSCALE 0.1803368801111204f   // 1/sqrt(64) * log2(e): softmax done in exp2 domain

__device__ inline short f2bf(float f) {
    union { float f; unsigned u; } x; x.f = f;
    unsigned r = x.u + 0x7fff + ((x.u >> 16) & 1);   // RNE
    return (short)(r >> 16);
}

// 16-lane butterfly reductions on the VALU via DPP (proven R5) — LDS pipe stays free.
__device__ inline float dpp_max16(float x) {
    int v;
    v = __builtin_amdgcn_update_dpp(0, __builtin_bit_cast(int, x), 0xB1, 0xF, 0xF, false);
    x = fmaxf(x, __builtin_bit_cast(float, v));
    v = __builtin_amdgcn_update_dpp(0, __builtin_bit_cast(int, x), 0x4E, 0xF, 0xF, false);
    x = fmaxf(x, __builtin_bit_cast(float, v));
    v = __builtin_amdgcn_update_dpp(0, __builtin_bit_cast(int, x), 0x141, 0xF, 0xF, false);
    x = fmaxf(x, __builtin_bit_cast(float, v));
    v = __builtin_amdgcn_update_dpp(0, __builtin_bit_cast(int, x), 0x140, 0xF, 0xF, false);
    x = fmaxf(x, __builtin_bit_cast(float, v));
    return x;
}
__device__ inline float dpp_sum16(float x) {
    int v;
    v = __builtin_amdgcn_update_dpp(0, __builtin_bit_cast(int, x), 0xB1, 0xF, 0xF, false);
    x += __builtin_bit_cast(float, v);
    v = __builtin_amdgcn_update_dpp(0, __builtin_bit_cast(int, x), 0x4E, 0xF, 0xF, false);
    x += __builtin_bit_cast(float, v);
    v = __builtin_amdgcn_update_dpp(0, __builtin_bit_cast(int, x), 0x141, 0xF, 0xF, false);
    x += __builtin_bit_cast(float, v);
    v = __builtin_amdgcn_update_dpp(0, __builtin_bit_cast(int, x), 0x140, 0xF, 0xF, false);
    x += __builtin_bit_cast(float, v);
    return x;
}

// ---------------- kernel 1: fp32 -> bf16 cast of residual ----------------
__global__ __launch_bounds__(256) void cast_kernel(const float* __restrict__ x,
                                                   short* __restrict__ y, int n) {
    int i = (blockIdx.x * 256 + threadIdx.x) * 8;
    if (i < n) {
        float4 a = *(const float4*)(x + i);
        float4 b = *(const float4*)(x + i + 4);
        bf16x8 o;
        o[0]=f2bf(a.x); o[1]=f2bf(a.y); o[2]=f2bf(a.z); o[3]=f2bf(a.w);
        o[4]=f2bf(b.x); o[5]=f2bf(b.y); o[6]=f2bf(b.z); o[7]=f2bf(b.w);
        *(bf16x8*)(y + i) = o;
    }
}

// ---------------- kernel 1b: transpose+cast weights to bf16 [n][k] ----------------
__global__ __launch_bounds__(256) void wtrans_kernel(
    const float* __restrict__ Wq, const float* __restrict__ Wk,
    const float* __restrict__ Wv, const float* __restrict__ Wo,
    short* __restrict__ Wt, short* __restrict__ Wot) {
    const int kt = blockIdx.x, yy = blockIdx.y, z = blockIdx.z;
    __shared__ short T[64 * 72];
    const int tid = threadIdx.x;
    const int r = tid >> 2, c0 = (tid & 3) * 16;
    const float* src;
    if (z < 3) {
        const float* W = z == 0 ? Wq : (z == 1 ? Wk : Wv);
        src = &W[yy * (D_ * A_) + (kt * 64 + r) * A_ + c0];
    } else {
        src = &Wo[(kt * 64 + r) * D_ + yy * 64 + c0];
    }
    #pragma unroll
    for (int q = 0; q < 4; q++) {
        float4 f = *(const float4*)(src + q * 4);
        T[r * 72 + c0 + q * 4 + 0] = f2bf(f.x);
        T[r * 72 + c0 + q * 4 + 1] = f2bf(f.y);
        T[r * 72 + c0 + q * 4 + 2] = f2bf(f.z);
        T[r * 72 + c0 + q * 4 + 3] = f2bf(f.w);
    }
    __syncthreads();
    const int a = tid >> 2, kc = (tid & 3) * 16;
    bf16x8 o0, o1;
    #pragma unroll
    for (int j = 0; j < 8; j++) {
        o0[j] = T[(kc + j) * 72 + a];
        o1[j] = T[(kc + 8 + j) * 72 + a];
    }
    const int n_base = (z < 3) ? z * 1024 + yy * 64 : yy * 64;
    short* dst = (z < 3) ? &Wt[(n_base + a) * D_ + kt * 64 + kc]
                         : &Wot[(n_base + a) * D_ + kt * 64 + kc];
    *(bf16x8*)dst = o0;
    *(bf16x8*)(dst + 8) = o1;
}

// ---------------- kernel 2: QKV as one GEMM [4096 x 3072 x 1024] ----------------
__global__ __launch_bounds__(256) void qkv_gemm(
    const short* __restrict__ X, const short* __restrict__ Wt,
    const float* __restrict__ bq, const float* __restrict__ bk, const float* __restrict__ bv,
    short* __restrict__ Qb, short* __restrict__ Kb, short* __restrict__ Vt) {
    const int mt = blockIdx.x, nt = blockIdx.y;
    const int m0 = mt * 128, n0 = nt * 128;
    const int sel = n0 >> 10;
    __shared__ short Xl[2][128 * 40], Wl[2][128 * 40];
    const int tid = threadIdx.x, wv = tid >> 6, lane = tid & 63, quad = lane >> 4, l16 = lane & 15;
    const int grow = tid >> 1, gk = (tid & 1) * 16;
    f32x4 acc[4][4] = {};
    bf16x8 xr0, xr1, wr0, wr1;
    {
        const short* xs = &X[(m0 + grow) * D_ + gk];
        xr0 = *(const bf16x8*)xs; xr1 = *(const bf16x8*)(xs + 8);
        const short* wsp = &Wt[(n0 + grow) * D_ + gk];
        wr0 = *(const bf16x8*)wsp; wr1 = *(const bf16x8*)(wsp + 8);
    }
    const int rm = (wv & 1) * 64, cn = (wv >> 1) * 64;
    for (int i = 0; i < 32; i++) {
        const int bu = i & 1;
        *(bf16x8*)&Xl[bu][grow * 40 + gk]     = xr0;
        *(bf16x8*)&Xl[bu][grow * 40 + gk + 8] = xr1;
        *(bf16x8*)&Wl[bu][grow * 40 + gk]     = wr0;
        *(bf16x8*)&Wl[bu][grow * 40 + gk + 8] = wr1;
        __syncthreads();
        if (i < 31) {
            const int k0 = (i + 1) * 32;
            const short* xs = &X[(m0 + grow) * D_ + k0 + gk];
            xr0 = *(const bf16x8*)xs; xr1 = *(const bf16x8*)(xs + 8);
            const short* wsp = &Wt[(n0 + grow) * D_ + k0 + gk];
            wr0 = *(const bf16x8*)wsp; wr1 = *(const bf16x8*)(wsp + 8);
        }
        bf16x8 af[4];
        #pragma unroll
        for (int rt = 0; rt < 4; rt++)
            af[rt] = *(bf16x8*)&Xl[bu][(rm + rt * 16 + l16) * 40 + quad * 8];
        #pragma unroll
        for (int ct = 0; ct < 4; ct++) {
            bf16x8 bf = *(bf16x8*)&Wl[bu][(cn + ct * 16 + l16) * 40 + quad * 8];
            #pragma unroll
            for (int rt = 0; rt < 4; rt++)
                acc[rt][ct] = __builtin_amdgcn_mfma_f32_16x16x32_bf16(af[rt], bf, acc[rt][ct], 0, 0, 0);
        }
    }
    const int b = m0 >> 11;
    const float* bias = sel == 0 ? bq : (sel == 1 ? bk : bv);
    if (sel < 2) {
        short* dst = sel == 0 ? Qb : Kb;
        const float scale = sel == 0 ? QSCALE : 1.0f;
        #pragma unroll
        for (int ct = 0; ct < 4; ct++) {
            const int n = n0 + cn + ct * 16 + l16;
            const int h = (n >> 6) & 15, a = n & 63;
            const float bi = bias[n & 1023];
            #pragma unroll
            for (int rt = 0; rt < 4; rt++)
                #pragma unroll
                for (int r = 0; r < 4; r++) {
                    const int row = m0 + rm + rt * 16 + quad * 4 + r;
                    const int s = row & (S_ - 1);
                    dst[(((b * H_) + h) * S_ + s) * A_ + a] = f2bf((acc[rt][ct][r] + bi) * scale);
                }
        }
    } else {
        #pragma unroll
        for (int ct = 0; ct < 4; ct++) {
            const int n = n0 + cn + ct * 16 + l16;
            const int h = (n >> 6) & 15, a = n & 63;
            const float bi = bias[n & 1023];
            #pragma unroll
            for (int rt = 0; rt < 4; rt++) {
                short4 pk;
                pk.x = f2bf(acc[rt][ct][0] + bi);
                pk.y = f2bf(acc[rt][ct][1] + bi);
                pk.z = f2bf(acc[rt][ct][2] + bi);
                pk.w = f2bf(acc[rt][ct][3] + bi);
                const int row = m0 + rm + rt * 16 + quad * 4;
                const int s = row & (S_ - 1);
                *(short4*)&Vt[(((b * H_) + h) * A_ + a) * S_ + s] = pk;
            }
        }
    }
}

// ---------------- kernel 3: flash attention — 8-wave blocks, SIMD-balanced pairing ----------------
// Block = 512 threads (8 waves). Waves 0-3 own q-tile qhi=31-p (rows wg*16..), waves 4-7 own
// qlo=p. K/V staged once per block (each thread stages ONE 16B slot, R5-verified mapping),
// double-buffered, ONE barrier/iter. Per SIMD the wave pair does (32-p)+(p+1)=33 updates —
// balanced — and 512 blocks x 8 waves = full chip at 4 waves/SIMD (chains overlap).
__global__ __launch_bounds__(512, 4) void flash_kernel(
    const short* __restrict__ Qb, const short* __restrict__ Kb,
    const short* __restrict__ Vt, short* __restrict__ Z) {
    const int p = blockIdx.x, h = blockIdx.y, b = blockIdx.z;
    const int bh = b * H_ + h;
    const int qlo = p, qhi = 31 - p;
    __shared__ short Kl[2][4096], Vl[2][4096];   // 16KB + 16KB
    __shared__ short Pl[8][1024];                // 16KB: per-wave P, A-frag-linear
    const int tid = threadIdx.x, wv = tid >> 6, lane = tid & 63, quad = lane >> 4, l16 = lane & 15;
    const int wg = wv & 3;                       // wave's row-group within its q-tile
    const int myqt = (wv < 4) ? qhi : qlo;
    short* Pw = &Pl[wv][0];
    // R5-verified P pack base: value (ct,r) -> Pw[pbase + (ct>>1)*512 + (ct&1)*256 + r*8]
    const int pbase = (l16 >> 3) * 128 + quad * 32 + (l16 & 7);

    // staging: thread owns slot L=tid (R5-verified slot->(row,col) mapping, 512 slots/tile)
    const int L = tid;
    const int srow = (L >> 7) * 16 + (L & 15);
    const int scol = ((L >> 6) & 1) * 32 + ((L >> 4) & 3) * 8;

    // Q A-fragment in registers (pre-scaled by QSCALE in qkv_gemm)
    const short* qptr = &Qb[(bh * S_ + myqt * 64 + wg * 16 + l16) * A_ + quad * 8];
    bf16x8 qf[2] = { *(const bf16x8*)qptr, *(const bf16x8*)(qptr + 32) };

    f32x4 O[4] = {};
    float m_i[4], l_i[4];
    #pragma unroll
    for (int r = 0; r < 4; r++) { m_i[r] = -1e30f; l_i[r] = 0.f; }

    bf16x8 kreg = *(const bf16x8*)&Kb[(bh * S_ + srow) * A_ + scol];
    bf16x8 vreg = *(const bf16x8*)&Vt[(bh * A_ + srow) * S_ + scol];

    for (int kt = 0; kt <= qhi; kt++) {
        const int bu = kt & 1;
        *(bf16x8*)&Kl[bu][L * 8] = kreg;
        *(bf16x8*)&Vl[bu][L * 8] = vreg;
        __syncthreads();
        if (kt < qhi) {   // prefetch kt+1 while computing kt
            kreg = *(const bf16x8*)&Kb[(bh * S_ + (kt + 1) * 64 + srow) * A_ + scol];
            vreg = *(const bf16x8*)&Vt[(bh * A_ + srow) * S_ + (kt + 1) * 64 + scol];
        }
        if (kt <= myqt) {
            // QK^T: 8 conflict-free b128 frag reads
            f32x4 sacc[4] = {};
            #pragma unroll
            for (int kk = 0; kk < 2; kk++)
                #pragma unroll
                for (int ct = 0; ct < 4; ct++) {
                    bf16x8 kf = *(bf16x8*)&Kl[bu][((ct * 2 + kk) * 64 + lane) * 8];
                    sacc[ct] = __builtin_amdgcn_mfma_f32_16x16x32_bf16(qf[kk], kf, sacc[ct], 0, 0, 0);
                }
            if (kt == myqt) {   // diagonal: causal mask (log2-domain scores)
                #pragma unroll
                for (int ct = 0; ct < 4; ct++) {
                    const int cl = ct * 16 + l16;
                    #pragma unroll
                    for (int r = 0; r < 4; r++)
                        if (cl > wg * 16 + quad * 4 + r) sacc[ct][r] = -1e30f;
                }
            }
            // online softmax: rows at (quad,r), kcols span (ct,l16); DPP reduce across l16
            #pragma unroll
            for (int r = 0; r < 4; r++) {
                float v = fmaxf(fmaxf(sacc[0][r], sacc[1][r]), fmaxf(sacc[2][r], sacc[3][r]));
                v = dpp_max16(v);
                const float mn = fmaxf(m_i[r], v);
                const float alpha = exp2f(m_i[r] - mn);
                float rs = 0.f;
                #pragma unroll
                for (int ct = 0; ct < 4; ct++) {
                    const float pe = exp2f(sacc[ct][r] - mn);
                    sacc[ct][r] = pe; rs += pe;
                }
                l_i[r] = l_i[r] * alpha + rs;   // per-lane partial; reduced in epilogue
                m_i[r] = mn;
                #pragma unroll
                for (int ct = 0; ct < 4; ct++) O[ct][r] *= alpha;
            }
            // P: C-layout -> A-frag-linear wave-private LDS (R5-verified pack)
            #pragma unroll
            for (int ct = 0; ct < 4; ct++) {
                const int cb = pbase + (ct >> 1) * 512 + (ct & 1) * 256;
                #pragma unroll
                for (int r = 0; r < 4; r++)
                    Pw[cb + r * 8] = f2bf(sacc[ct][r]);
            }
            __builtin_amdgcn_s_waitcnt(0xC07F);   // lgkmcnt(0): wave-private LDS dep
            bf16x8 pa0 = *(bf16x8*)&Pw[lane * 8];
            bf16x8 pa1 = *(bf16x8*)&Pw[(64 + lane) * 8];
            #pragma unroll
            for (int kk = 0; kk < 2; kk++)
                #pragma unroll
                for (int ct = 0; ct < 4; ct++) {
                    bf16x8 vf = *(bf16x8*)&Vl[bu][((ct * 2 + kk) * 64 + lane) * 8];
                    O[ct] = __builtin_amdgcn_mfma_f32_16x16x32_bf16(kk ? pa1 : pa0, vf, O[ct], 0, 0, 0);
                }
        }
        // single barrier per iter; next iter stages the other buffer
    }
    // epilogue: reduce l partials across l16, write Z[b, s, h*64+a]
    float lsum[4];
    #pragma unroll
    for (int r = 0; r < 4; r++) lsum[r] = dpp_sum16(l_i[r]);
    #pragma unroll
    for (int ct = 0; ct < 4; ct++) {
        const int a = ct * 16 + l16;
        #pragma unroll
        for (int r = 0; r < 4; r++) {
            const int s = myqt * 64 + wg * 16 + quad * 4 + r;
            Z[(b * S_ + s) * (H_ * A_) + h * A_ + a] = f2bf(O[ct][r] / lsum[r]);
        }
    }
}

// ---------------- kernel 4: output projection GEMM [4096 x 1024 x 1024] ----------------
__global__ __launch_bounds__(256) void proj_gemm(
    const short* __restrict__ Zb, const short* __restrict__ Wot,
    const float* __restrict__ bo, float* __restrict__ out) {
    const int mt = blockIdx.x, nt = blockIdx.y;
    const int m0 = mt * 128, n0 = nt * 128;
    __shared__ short Xl[2][128 * 40], Wl[2][128 * 40];
    const int tid = threadIdx.x, wv = tid >> 6, lane = tid & 63, quad = lane >> 4, l16 = lane & 15;
    const int grow = tid >> 1, gk = (tid & 1) * 16;
    f32x4 acc[4][4] = {};
    bf16x8 xr0, xr1, wr0, wr1;
    {
        const short* xs = &Zb[(m0 + grow) * D_ + gk];
        xr0 = *(const bf16x8*)xs; xr1 = *(const bf16x8*)(xs + 8);
        const short* wsp = &Wot[(n0 + grow) * D_ + gk];
        wr0 = *(const bf16x8*)wsp; wr1 = *(const bf16x8*)(wsp + 8);
    }
    const int rm = (wv & 1) * 64, cn = (wv >> 1) * 64;
    for (int i = 0; i < 32; i++) {
        const int bu = i & 1;
        *(bf16x8*)&Xl[bu][grow * 40 + gk]     = xr0;
        *(bf16x8*)&Xl[bu][grow * 40 + gk + 8] = xr1;
        *(bf16x8*)&Wl[bu][grow * 40 + gk]     = wr0;
        *(bf16x8*)&Wl[bu][grow * 40 + gk + 8] = wr1;
        __syncthreads();
        if (i < 31) {
            const int k0 = (i + 1) * 32;
            const short* xs = &Zb[(m0 + grow) * D_ + k0 + gk];
            xr0 = *(const bf16x8*)xs; xr1 = *(const bf16x8*)(xs + 8);
            const short* wsp = &Wot[(n0 + grow) * D_ + k0 + gk];
            wr0 = *(const bf16x8*)wsp; wr1 = *(const bf16x8*)(wsp + 8);
        }
        bf16x8 af[4];
        #pragma unroll
        for (int rt = 0; rt < 4; rt++)
            af[rt] = *(bf16x8*)&Xl[bu][(rm + rt * 16 + l16) * 40 + quad * 8];
        #pragma unroll
        for (int ct = 0; ct < 4; ct++) {
            bf16x8 bf = *(bf16x8*)&Wl[bu][(cn + ct * 16 + l16) * 40 + quad * 8];
            #pragma unroll
            for (int rt = 0; rt < 4; rt++)
                acc[rt][ct] = __builtin_amdgcn_mfma_f32_16x16x32_bf16(af[rt], bf, acc[rt][ct], 0, 0, 0);
        }
    }
    #pragma unroll
    for (int ct = 0; ct < 4; ct++) {
        const int n = n0 + cn + ct * 16 + l16;
        const float bi = bo[n];
        #pragma unroll
        for (int rt = 0; rt < 4; rt++)
            #pragma unroll
            for (int r = 0; r < 4; r++) {
                const int row = m0 + rm + rt * 16 + quad * 4 + r;
                out[row * D_ + n] = acc[rt][ct][r] + bi;
            }
    }
}

extern "C" void kernel_launch(void* const* d_in, const int* in_sizes, int n_in,
                              void* d_out, int out_size, void* d_ws, size_t ws_size,
                              hipStream_t stream) {
    const float* residual = (const float*)d_in[0];
    const float* Wq = (const float*)d_in[1];
    const float* Wk = (const float*)d_in[2];
    const float* Wv = (const float*)d_in[3];
    const float* Wo = (const float*)d_in[4];
    const float* bq = (const float*)d_in[5];
    const float* bk = (const float*)d_in[6];
    const float* bv = (const float*)d_in[7];
    const float* bo = (const float*)d_in[8];
    float* out = (float*)d_out;

    char* ws = (char*)d_ws;
    const size_t NE = (size_t)B_ * S_ * D_;           // 4,194,304
    short* Xbf = (short*)(ws);                        //  8 MB  [B*S, D] bf16
    short* Wt  = (short*)(ws +  8ull * 1024 * 1024);  //  6 MB  [3072, 1024] bf16 (qkv, transposed)
    short* Wot = (short*)(ws + 14ull * 1024 * 1024);  //  2 MB  [1024, 1024] bf16 (Wo, transposed)
    short* Qb  = (short*)(ws + 16ull * 1024 * 1024);  //  8 MB  [B,H,S,A]
    short* Kb  = (short*)(ws + 24ull * 1024 * 1024);  //  8 MB  [B,H,S,A]
    short* Vt  = (short*)(ws + 32ull * 1024 * 1024);  //  8 MB  [B,H,A,S]
    short* Zb  = (short*)(ws + 40ull * 1024 * 1024);  //  8 MB  [B,S,H*A]

    hipLaunchKernelGGL(cast_kernel, dim3((int)(NE / (256 * 8))), dim3(256), 0, stream,
                       residual, Xbf, (int)NE);
    hipLaunchKernelGGL(wtrans_kernel, dim3(16, 16, 4), dim3(256), 0, stream,
                       Wq, Wk, Wv, Wo, Wt, Wot);
    hipLaunchKernelGGL(qkv_gemm, dim3(32, 24), dim3(256), 0, stream,
                       Xbf, Wt, bq, bk, bv, Qb, Kb, Vt);
    hipLaunchKernelGGL(flash_kernel, dim3(16, H_, B_), dim3(512), 0, stream,
                       Qb, Kb, Vt, Zb);
    hipLaunchKernelGGL(proj_gemm, dim3(32, 8), dim3(256), 0, stream,
                       Zb, Wot, bo, out);
}

// Round 10
// 209.727 us; speedup vs baseline: 1.8364x; 1.0155x over previous
//
#include <hip/hip_runtime.h>
#include <hip/hip_bf16.h>

// Problem constants: B=2, S=2048, D=1024, H=16, A=64
#define B_ 2
#define S_ 2048
#define D_ 1024
#define H_ 16
#define A_ 64

typedef __attribute__((ext_vector_type(8))) short bf16x8;
typedef __attribute__((ext_vector_type(4))) float f32x4;

#define QSCALE 0.1803368801111204f   // 1/sqrt(64) * log2(e): softmax done in exp2 domain

__device__ inline short f2bf(float f) {
    union { float f; unsigned u; } x; x.f = f;
    unsigned r = x.u + 0x7fff + ((x.u >> 16) & 1);   // RNE
    return (short)(r >> 16);
}

// 16-lane butterfly reductions on the VALU via DPP (proven R5/R8) — LDS pipe stays free.
__device__ inline float dpp_max16(float x) {
    int v;
    v = __builtin_amdgcn_update_dpp(0, __builtin_bit_cast(int, x), 0xB1, 0xF, 0xF, false);
    x = fmaxf(x, __builtin_bit_cast(float, v));
    v = __builtin_amdgcn_update_dpp(0, __builtin_bit_cast(int, x), 0x4E, 0xF, 0xF, false);
    x = fmaxf(x, __builtin_bit_cast(float, v));
    v = __builtin_amdgcn_update_dpp(0, __builtin_bit_cast(int, x), 0x141, 0xF, 0xF, false);
    x = fmaxf(x, __builtin_bit_cast(float, v));
    v = __builtin_amdgcn_update_dpp(0, __builtin_bit_cast(int, x), 0x140, 0xF, 0xF, false);
    x = fmaxf(x, __builtin_bit_cast(float, v));
    return x;
}
__device__ inline float dpp_sum16(float x) {
    int v;
    v = __builtin_amdgcn_update_dpp(0, __builtin_bit_cast(int, x), 0xB1, 0xF, 0xF, false);
    x += __builtin_bit_cast(float, v);
    v = __builtin_amdgcn_update_dpp(0, __builtin_bit_cast(int, x), 0x4E, 0xF, 0xF, false);
    x += __builtin_bit_cast(float, v);
    v = __builtin_amdgcn_update_dpp(0, __builtin_bit_cast(int, x), 0x141, 0xF, 0xF, false);
    x += __builtin_bit_cast(float, v);
    v = __builtin_amdgcn_update_dpp(0, __builtin_bit_cast(int, x), 0x140, 0xF, 0xF, false);
    x += __builtin_bit_cast(float, v);
    return x;
}

// ---------------- kernel 1: fp32 -> bf16 cast of residual ----------------
__global__ __launch_bounds__(256) void cast_kernel(const float* __restrict__ x,
                                                   short* __restrict__ y, int n) {
    int i = (blockIdx.x * 256 + threadIdx.x) * 8;
    if (i < n) {
        float4 a = *(const float4*)(x + i);
        float4 b = *(const float4*)(x + i + 4);
        bf16x8 o;
        o[0]=f2bf(a.x); o[1]=f2bf(a.y); o[2]=f2bf(a.z); o[3]=f2bf(a.w);
        o[4]=f2bf(b.x); o[5]=f2bf(b.y); o[6]=f2bf(b.z); o[7]=f2bf(b.w);
        *(bf16x8*)(y + i) = o;
    }
}

// ---------------- kernel 1b: transpose+cast weights to bf16 [n][k] ----------------
__global__ __launch_bounds__(256) void wtrans_kernel(
    const float* __restrict__ Wq, const float* __restrict__ Wk,
    const float* __restrict__ Wv, const float* __restrict__ Wo,
    short* __restrict__ Wt, short* __restrict__ Wot) {
    const int kt = blockIdx.x, yy = blockIdx.y, z = blockIdx.z;
    __shared__ short T[64 * 72];
    const int tid = threadIdx.x;
    const int r = tid >> 2, c0 = (tid & 3) * 16;
    const float* src;
    if (z < 3) {
        const float* W = z == 0 ? Wq : (z == 1 ? Wk : Wv);
        src = &W[yy * (D_ * A_) + (kt * 64 + r) * A_ + c0];
    } else {
        src = &Wo[(kt * 64 + r) * D_ + yy * 64 + c0];
    }
    #pragma unroll
    for (int q = 0; q < 4; q++) {
        float4 f = *(const float4*)(src + q * 4);
        T[r * 72 + c0 + q * 4 + 0] = f2bf(f.x);
        T[r * 72 + c0 + q * 4 + 1] = f2bf(f.y);
        T[r * 72 + c0 + q * 4 + 2] = f2bf(f.z);
        T[r * 72 + c0 + q * 4 + 3] = f2bf(f.w);
    }
    __syncthreads();
    const int a = tid >> 2, kc = (tid & 3) * 16;
    bf16x8 o0, o1;
    #pragma unroll
    for (int j = 0; j < 8; j++) {
        o0[j] = T[(kc + j) * 72 + a];
        o1[j] = T[(kc + 8 + j) * 72 + a];
    }
    const int n_base = (z < 3) ? z * 1024 + yy * 64 : yy * 64;
    short* dst = (z < 3) ? &Wt[(n_base + a) * D_ + kt * 64 + kc]
                         : &Wot[(n_base + a) * D_ + kt * 64 + kc];
    *(bf16x8*)dst = o0;
    *(bf16x8*)(dst + 8) = o1;
}

// ---------------- kernel 2: QKV as one GEMM [4096 x 3072 x 1024] (R8 verbatim) ----------------
__global__ __launch_bounds__(256) void qkv_gemm(
    const short* __restrict__ X, const short* __restrict__ Wt,
    const float* __restrict__ bq, const float* __restrict__ bk, const float* __restrict__ bv,
    short* __restrict__ Qb, short* __restrict__ Kb, short* __restrict__ Vt) {
    const int mt = blockIdx.x, nt = blockIdx.y;
    const int m0 = mt * 128, n0 = nt * 128;
    const int sel = n0 >> 10;
    __shared__ short Xl[2][128 * 40], Wl[2][128 * 40];
    const int tid = threadIdx.x, wv = tid >> 6, lane = tid & 63, quad = lane >> 4, l16 = lane & 15;
    const int grow = tid >> 1, gk = (tid & 1) * 16;
    f32x4 acc[4][4] = {};
    bf16x8 xr0, xr1, wr0, wr1;
    {
        const short* xs = &X[(m0 + grow) * D_ + gk];
        xr0 = *(const bf16x8*)xs; xr1 = *(const bf16x8*)(xs + 8);
        const short* wsp = &Wt[(n0 + grow) * D_ + gk];
        wr0 = *(const bf16x8*)wsp; wr1 = *(const bf16x8*)(wsp + 8);
    }
    const int rm = (wv & 1) * 64, cn = (wv >> 1) * 64;
    for (int i = 0; i < 32; i++) {
        const int bu = i & 1;
        *(bf16x8*)&Xl[bu][grow * 40 + gk]     = xr0;
        *(bf16x8*)&Xl[bu][grow * 40 + gk + 8] = xr1;
        *(bf16x8*)&Wl[bu][grow * 40 + gk]     = wr0;
        *(bf16x8*)&Wl[bu][grow * 40 + gk + 8] = wr1;
        __syncthreads();
        if (i < 31) {
            const int k0 = (i + 1) * 32;
            const short* xs = &X[(m0 + grow) * D_ + k0 + gk];
            xr0 = *(const bf16x8*)xs; xr1 = *(const bf16x8*)(xs + 8);
            const short* wsp = &Wt[(n0 + grow) * D_ + k0 + gk];
            wr0 = *(const bf16x8*)wsp; wr1 = *(const bf16x8*)(wsp + 8);
        }
        bf16x8 af[4];
        #pragma unroll
        for (int rt = 0; rt < 4; rt++)
            af[rt] = *(bf16x8*)&Xl[bu][(rm + rt * 16 + l16) * 40 + quad * 8];
        #pragma unroll
        for (int ct = 0; ct < 4; ct++) {
            bf16x8 bf = *(bf16x8*)&Wl[bu][(cn + ct * 16 + l16) * 40 + quad * 8];
            #pragma unroll
            for (int rt = 0; rt < 4; rt++)
                acc[rt][ct] = __builtin_amdgcn_mfma_f32_16x16x32_bf16(af[rt], bf, acc[rt][ct], 0, 0, 0);
        }
    }
    const int b = m0 >> 11;
    const float* bias = sel == 0 ? bq : (sel == 1 ? bk : bv);
    if (sel < 2) {
        short* dst = sel == 0 ? Qb : Kb;
        const float scale = sel == 0 ? QSCALE : 1.0f;
        #pragma unroll
        for (int ct = 0; ct < 4; ct++) {
            const int n = n0 + cn + ct * 16 + l16;
            const int h = (n >> 6) & 15, a = n & 63;
            const float bi = bias[n & 1023];
            #pragma unroll
            for (int rt = 0; rt < 4; rt++)
                #pragma unroll
                for (int r = 0; r < 4; r++) {
                    const int row = m0 + rm + rt * 16 + quad * 4 + r;
                    const int s = row & (S_ - 1);
                    dst[(((b * H_) + h) * S_ + s) * A_ + a] = f2bf((acc[rt][ct][r] + bi) * scale);
                }
        }
    } else {
        #pragma unroll
        for (int ct = 0; ct < 4; ct++) {
            const int n = n0 + cn + ct * 16 + l16;
            const int h = (n >> 6) & 15, a = n & 63;
            const float bi = bias[n & 1023];
            #pragma unroll
            for (int rt = 0; rt < 4; rt++) {
                short4 pk;
                pk.x = f2bf(acc[rt][ct][0] + bi);
                pk.y = f2bf(acc[rt][ct][1] + bi);
                pk.z = f2bf(acc[rt][ct][2] + bi);
                pk.w = f2bf(acc[rt][ct][3] + bi);
                const int row = m0 + rm + rt * 16 + quad * 4;
                const int s = row & (S_ - 1);
                *(short4*)&Vt[(((b * H_) + h) * A_ + a) * S_ + s] = pk;
            }
        }
    }
}

// ---------------- kernel 3: flash attention — 8-wave blocks, SIMD-balanced pairing (R8 verbatim) ----------------
__global__ __launch_bounds__(512, 4) void flash_kernel(
    const short* __restrict__ Qb, const short* __restrict__ Kb,
    const short* __restrict__ Vt, short* __restrict__ Z) {
    const int p = blockIdx.x, h = blockIdx.y, b = blockIdx.z;
    const int bh = b * H_ + h;
    const int qlo = p, qhi = 31 - p;
    __shared__ short Kl[2][4096], Vl[2][4096];
    __shared__ short Pl[8][1024];
    const int tid = threadIdx.x, wv = tid >> 6, lane = tid & 63, quad = lane >> 4, l16 = lane & 15;
    const int wg = wv & 3;
    const int myqt = (wv < 4) ? qhi : qlo;
    short* Pw = &Pl[wv][0];
    const int pbase = (l16 >> 3) * 128 + quad * 32 + (l16 & 7);

    const int L = tid;
    const int srow = (L >> 7) * 16 + (L & 15);
    const int scol = ((L >> 6) & 1) * 32 + ((L >> 4) & 3) * 8;

    const short* qptr = &Qb[(bh * S_ + myqt * 64 + wg * 16 + l16) * A_ + quad * 8];
    bf16x8 qf[2] = { *(const bf16x8*)qptr, *(const bf16x8*)(qptr + 32) };

    f32x4 O[4] = {};
    float m_i[4], l_i[4];
    #pragma unroll
    for (int r = 0; r < 4; r++) { m_i[r] = -1e30f; l_i[r] = 0.f; }

    bf16x8 kreg = *(const bf16x8*)&Kb[(bh * S_ + srow) * A_ + scol];
    bf16x8 vreg = *(const bf16x8*)&Vt[(bh * A_ + srow) * S_ + scol];

    for (int kt = 0; kt <= qhi; kt++) {
        const int bu = kt & 1;
        *(bf16x8*)&Kl[bu][L * 8] = kreg;
        *(bf16x8*)&Vl[bu][L * 8] = vreg;
        __syncthreads();
        if (kt < qhi) {
            kreg = *(const bf16x8*)&Kb[(bh * S_ + (kt + 1) * 64 + srow) * A_ + scol];
            vreg = *(const bf16x8*)&Vt[(bh * A_ + srow) * S_ + (kt + 1) * 64 + scol];
        }
        if (kt <= myqt) {
            f32x4 sacc[4] = {};
            #pragma unroll
            for (int kk = 0; kk < 2; kk++)
                #pragma unroll
                for (int ct = 0; ct < 4; ct++) {
                    bf16x8 kf = *(bf16x8*)&Kl[bu][((ct * 2 + kk) * 64 + lane) * 8];
                    sacc[ct] = __builtin_amdgcn_mfma_f32_16x16x32_bf16(qf[kk], kf, sacc[ct], 0, 0, 0);
                }
            if (kt == myqt) {
                #pragma unroll
                for (int ct = 0; ct < 4; ct++) {
                    const int cl = ct * 16 + l16;
                    #pragma unroll
                    for (int r = 0; r < 4; r++)
                        if (cl > wg * 16 + quad * 4 + r) sacc[ct][r] = -1e30f;
                }
            }
            #pragma unroll
            for (int r = 0; r < 4; r++) {
                float v = fmaxf(fmaxf(sacc[0][r], sacc[1][r]), fmaxf(sacc[2][r], sacc[3][r]));
                v = dpp_max16(v);
                const float mn = fmaxf(m_i[r], v);
                const float alpha = exp2f(m_i[r] - mn);
                float rs = 0.f;
                #pragma unroll
                for (int ct = 0; ct < 4; ct++) {
                    const float pe = exp2f(sacc[ct][r] - mn);
                    sacc[ct][r] = pe; rs += pe;
                }
                l_i[r] = l_i[r] * alpha + rs;
                m_i[r] = mn;
                #pragma unroll
                for (int ct = 0; ct < 4; ct++) O[ct][r] *= alpha;
            }
            #pragma unroll
            for (int ct = 0; ct < 4; ct++) {
                const int cb = pbase + (ct >> 1) * 512 + (ct & 1) * 256;
                #pragma unroll
                for (int r = 0; r < 4; r++)
                    Pw[cb + r * 8] = f2bf(sacc[ct][r]);
            }
            __builtin_amdgcn_s_waitcnt(0xC07F);   // lgkmcnt(0): wave-private LDS dep
            bf16x8 pa0 = *(bf16x8*)&Pw[lane * 8];
            bf16x8 pa1 = *(bf16x8*)&Pw[(64 + lane) * 8];
            #pragma unroll
            for (int kk = 0; kk < 2; kk++)
                #pragma unroll
                for (int ct = 0; ct < 4; ct++) {
                    bf16x8 vf = *(bf16x8*)&Vl[bu][((ct * 2 + kk) * 64 + lane) * 8];
                    O[ct] = __builtin_amdgcn_mfma_f32_16x16x32_bf16(kk ? pa1 : pa0, vf, O[ct], 0, 0, 0);
                }
        }
    }
    float lsum[4];
    #pragma unroll
    for (int r = 0; r < 4; r++) lsum[r] = dpp_sum16(l_i[r]);
    #pragma unroll
    for (int ct = 0; ct < 4; ct++) {
        const int a = ct * 16 + l16;
        #pragma unroll
        for (int r = 0; r < 4; r++) {
            const int s = myqt * 64 + wg * 16 + quad * 4 + r;
            Z[(b * S_ + s) * (H_ * A_) + h * A_ + a] = f2bf(O[ct][r] / lsum[r]);
        }
    }
}

// ---------------- kernel 4: output projection GEMM [4096 x 1024 x 1024] ----------------
// ONLY change vs R8: tile 128x64 (grid 32x16 = 512 blocks -> 2 blocks/CU, 2 waves/SIMD
// instead of 1). Wave mapping: rm=(wv&1)*64 (unchanged), cn=(wv>>1)*32, acc[4][2].
// W tile 64x32 staged by threads 0-127 with the same grow/gk map. Fragment math identical.
__global__ __launch_bounds__(256) void proj_gemm(
    const short* __restrict__ Zb, const short* __restrict__ Wot,
    const float* __restrict__ bo, float* __restrict__ out) {
    const int mt = blockIdx.x, nt = blockIdx.y;
    const int m0 = mt * 128, n0 = nt * 64;
    __shared__ short Xl[2][128 * 40], Wl[2][64 * 40];
    const int tid = threadIdx.x, wv = tid >> 6, lane = tid & 63, quad = lane >> 4, l16 = lane & 15;
    const int grow = tid >> 1, gk = (tid & 1) * 16;
    const bool doW = (tid < 128);          // W tile 64x32 = 2048 shorts = 128 thr x 16
    f32x4 acc[4][2] = {};
    bf16x8 xr0, xr1, wr0, wr1;
    {
        const short* xs = &Zb[(m0 + grow) * D_ + gk];
        xr0 = *(const bf16x8*)xs; xr1 = *(const bf16x8*)(xs + 8);
        if (doW) {
            const short* wsp = &Wot[(n0 + grow) * D_ + gk];
            wr0 = *(const bf16x8*)wsp; wr1 = *(const bf16x8*)(wsp + 8);
        }
    }
    const int rm = (wv & 1) * 64, cn = (wv >> 1) * 32;
    for (int i = 0; i < 32; i++) {
        const int bu = i & 1;
        *(bf16x8*)&Xl[bu][grow * 40 + gk]     = xr0;
        *(bf16x8*)&Xl[bu][grow * 40 + gk + 8] = xr1;
        if (doW) {
            *(bf16x8*)&Wl[bu][grow * 40 + gk]     = wr0;
            *(bf16x8*)&Wl[bu][grow * 40 + gk + 8] = wr1;
        }
        __syncthreads();
        if (i < 31) {
            const int k0 = (i + 1) * 32;
            const short* xs = &Zb[(m0 + grow) * D_ + k0 + gk];
            xr0 = *(const bf16x8*)xs; xr1 = *(const bf16x8*)(xs + 8);
            if (doW) {
                const short* wsp = &Wot[(n0 + grow) * D_ + k0 + gk];
                wr0 = *(const bf16x8*)wsp; wr1 = *(const bf16x8*)(wsp + 8);
            }
        }
        bf16x8 af[4];
        #pragma unroll
        for (int rt = 0; rt < 4; rt++)
            af[rt] = *(bf16x8*)&Xl[bu][(rm + rt * 16 + l16) * 40 + quad * 8];
        #pragma unroll
        for (int ct = 0; ct < 2; ct++) {
            bf16x8 bf = *(bf16x8*)&Wl[bu][(cn + ct * 16 + l16) * 40 + quad * 8];
            #pragma unroll
            for (int rt = 0; rt < 4; rt++)
                acc[rt][ct] = __builtin_amdgcn_mfma_f32_16x16x32_bf16(af[rt], bf, acc[rt][ct], 0, 0, 0);
        }
    }
    #pragma unroll
    for (int ct = 0; ct < 2; ct++) {
        const int n = n0 + cn + ct * 16 + l16;
        const float bi = bo[n];
        #pragma unroll
        for (int rt = 0; rt < 4; rt++)
            #pragma unroll
            for (int r = 0; r < 4; r++) {
                const int row = m0 + rm + rt * 16 + quad * 4 + r;
                out[row * D_ + n] = acc[rt][ct][r] + bi;
            }
    }
}

extern "C" void kernel_launch(void* const* d_in, const int* in_sizes, int n_in,
                              void* d_out, int out_size, void* d_ws, size_t ws_size,
                              hipStream_t stream) {
    const float* residual = (const float*)d_in[0];
    const float* Wq = (const float*)d_in[1];
    const float* Wk = (const float*)d_in[2];
    const float* Wv = (const float*)d_in[3];
    const float* Wo = (const float*)d_in[4];
    const float* bq = (const float*)d_in[5];
    const float* bk = (const float*)d_in[6];
    const float* bv = (const float*)d_in[7];
    const float* bo = (const float*)d_in[8];
    float* out = (float*)d_out;

    char* ws = (char*)d_ws;
    const size_t NE = (size_t)B_ * S_ * D_;           // 4,194,304
    short* Xbf = (short*)(ws);                        //  8 MB  [B*S, D] bf16
    short* Wt  = (short*)(ws +  8ull * 1024 * 1024);  //  6 MB  [3072, 1024] bf16 (qkv, transposed)
    short* Wot = (short*)(ws + 14ull * 1024 * 1024);  //  2 MB  [1024, 1024] bf16 (Wo, transposed)
    short* Qb  = (short*)(ws + 16ull * 1024 * 1024);  //  8 MB  [B,H,S,A]
    short* Kb  = (short*)(ws + 24ull * 1024 * 1024);  //  8 MB  [B,H,S,A]
    short* Vt  = (short*)(ws + 32ull * 1024 * 1024);  //  8 MB  [B,H,A,S]
    short* Zb  = (short*)(ws + 40ull * 1024 * 1024);  //  8 MB  [B,S,H*A]

    hipLaunchKernelGGL(cast_kernel, dim3((int)(NE / (256 * 8))), dim3(256), 0, stream,
                       residual, Xbf, (int)NE);
    hipLaunchKernelGGL(wtrans_kernel, dim3(16, 16, 4), dim3(256), 0, stream,
                       Wq, Wk, Wv, Wo, Wt, Wot);
    hipLaunchKernelGGL(qkv_gemm, dim3(32, 24), dim3(256), 0, stream,
                       Xbf, Wt, bq, bk, bv, Qb, Kb, Vt);
    hipLaunchKernelGGL(flash_kernel, dim3(16, H_, B_), dim3(512), 0, stream,
                       Qb, Kb, Vt, Zb);
    hipLaunchKernelGGL(proj_gemm, dim3(32, 16), dim3(256), 0, stream,
                       Zb, Wot, bo, out);
}